// Round 1
// baseline (425.549 us; speedup 1.0000x reference)
//
#include <hip/hip_runtime.h>
#include <hip/hip_bf16.h>

typedef __attribute__((ext_vector_type(8))) short short8;
typedef __attribute__((ext_vector_type(4))) float f32x4;
typedef __attribute__((ext_vector_type(4))) unsigned short u16x4;
typedef __hip_bfloat16 bf16;

#define GLD_LDS16(g, l) __builtin_amdgcn_global_load_lds(                      \
    (const __attribute__((address_space(1))) void*)(g),                        \
    (__attribute__((address_space(3))) void*)(l), 16, 0, 0)

static __device__ __forceinline__ f32x4 mfma16(short8 a, short8 b, f32x4 c) {
  return __builtin_amdgcn_mfma_f32_16x16x32_bf16(a, b, c, 0, 0, 0);
}

// ---------------- fp32 -> bf16 convert (vectorized, exact-grid) -------------
__global__ __launch_bounds__(256) void k_cvt(const float* __restrict__ in,
                                             bf16* __restrict__ out) {
  long i = (long)blockIdx.x * 256 + threadIdx.x;
  f32x4 v = *(const f32x4*)(in + i * 4);
  u16x4 o;
#pragma unroll
  for (int j = 0; j < 4; ++j)
    o[j] = __builtin_bit_cast(unsigned short, __float2bfloat16(v[j]));
  *(u16x4*)((unsigned short*)out + i * 4) = o;
}

// ---------------- 128x128 bf16 GEMM, B stored [N][K] (K-major) --------------
// epi==0: scatter into Q/K/V  [bh][2048][64]
// epi==1: fp32 out[t*N+e] = acc + bias[e]
__global__ __launch_bounds__(256) void k_gemm(
    const bf16* __restrict__ A, const bf16* __restrict__ B,
    int M, int N, int K, int epi,
    bf16* __restrict__ Qb, bf16* __restrict__ Kb, bf16* __restrict__ Vb,
    float* __restrict__ Out, const float* __restrict__ bias) {
  __shared__ bf16 lA[4096];  // 128 x 32
  __shared__ bf16 lB[4096];  // 128 x 32
  const int tid = threadIdx.x, w = tid >> 6, l = tid & 63;
  const int m0 = blockIdx.x * 128, n0 = blockIdx.y * 128;
  const int wrow = (w >> 1) * 64, wcol = (w & 1) * 64;
  const int fr = l & 15, fq = l >> 4;
  f32x4 acc[4][4] = {};
  const int c0 = w * 64 + l, c1 = c0 + 256;  // 16B chunk ids
  const bf16* Ag0 = A + (size_t)(m0 + (c0 >> 2)) * K + (c0 & 3) * 8;
  const bf16* Ag1 = A + (size_t)(m0 + (c1 >> 2)) * K + (c1 & 3) * 8;
  const bf16* Bg0 = B + (size_t)(n0 + (c0 >> 2)) * K + (c0 & 3) * 8;
  const bf16* Bg1 = B + (size_t)(n0 + (c1 >> 2)) * K + (c1 & 3) * 8;
  bf16* lA0 = &lA[w * 512];
  bf16* lA1 = &lA[2048 + w * 512];
  bf16* lB0 = &lB[w * 512];
  bf16* lB1 = &lB[2048 + w * 512];

  for (int k0 = 0; k0 < K; k0 += 32) {
    __syncthreads();  // previous compute done before overwrite
    GLD_LDS16(Ag0 + k0, lA0);
    GLD_LDS16(Ag1 + k0, lA1);
    GLD_LDS16(Bg0 + k0, lB0);
    GLD_LDS16(Bg1 + k0, lB1);
    __syncthreads();  // drains vmcnt -> staged data visible
    short8 af[4], bfv[4];
#pragma unroll
    for (int mi = 0; mi < 4; ++mi)
      af[mi] = *(const short8*)&lA[(wrow + mi * 16 + fr) * 32 + fq * 8];
#pragma unroll
    for (int ni = 0; ni < 4; ++ni)
      bfv[ni] = *(const short8*)&lB[(wcol + ni * 16 + fr) * 32 + fq * 8];
#pragma unroll
    for (int mi = 0; mi < 4; ++mi)
#pragma unroll
      for (int ni = 0; ni < 4; ++ni)
        acc[mi][ni] = mfma16(af[mi], bfv[ni], acc[mi][ni]);
  }

  const int lrow = fq * 4;
  if (epi == 0) {
#pragma unroll
    for (int mi = 0; mi < 4; ++mi)
#pragma unroll
      for (int ni = 0; ni < 4; ++ni)
#pragma unroll
        for (int r = 0; r < 4; ++r) {
          int t = m0 + wrow + mi * 16 + lrow + r;
          int e = n0 + wcol + ni * 16 + fr;
          int sect = e >> 10, eh = (e >> 6) & 15, dh = e & 63;
          int b = t >> 11, tt = t & 2047;
          size_t idx = (((size_t)b * 16 + eh) * 2048 + tt) * 64 + dh;
          bf16 val = __float2bfloat16(acc[mi][ni][r]);
          if (sect == 0) Qb[idx] = val;
          else if (sect == 1) Kb[idx] = val;
          else Vb[idx] = val;
        }
  } else {
#pragma unroll
    for (int mi = 0; mi < 4; ++mi)
#pragma unroll
      for (int ni = 0; ni < 4; ++ni)
#pragma unroll
        for (int r = 0; r < 4; ++r) {
          int t = m0 + wrow + mi * 16 + lrow + r;
          int e = n0 + wcol + ni * 16 + fr;
          Out[(size_t)t * N + e] = acc[mi][ni][r] + bias[e];
        }
  }
}

// ---------------- V transpose: [bh][2048][64] -> [bh][64][2048] -------------
__global__ __launch_bounds__(256) void k_trv(const bf16* __restrict__ Vb,
                                             bf16* __restrict__ Vt) {
  __shared__ bf16 tile[64][80];  // 160B row stride, 16B aligned
  const int bh = blockIdx.y, t0 = blockIdx.x * 64;
  const int tid = threadIdx.x;
#pragma unroll
  for (int it = 0; it < 2; ++it) {
    int idx = tid + it * 256;
    int r = idx >> 3, c8 = (idx & 7) * 8;
    short8 v = *(const short8*)(Vb + ((size_t)bh * 2048 + t0 + r) * 64 + c8);
    *(short8*)&tile[r][c8] = v;
  }
  __syncthreads();
#pragma unroll
  for (int it = 0; it < 2; ++it) {
    int idx = tid + it * 256;
    int d = idx >> 3, c8 = (idx & 7) * 8;
    short8 o;
#pragma unroll
    for (int j = 0; j < 8; ++j)
      o[j] = __builtin_bit_cast(short, tile[c8 + j][d]);
    *(short8*)(Vt + ((size_t)bh * 64 + d) * 2048 + t0 + c8) = o;
  }
}

// ---------------- flash attention with relative-position bias ---------------
// grid: (32 q-tiles of 64, 32 bh). 4 waves/block, wave owns 16 q-rows.
__global__ __launch_bounds__(256) void k_attn(
    const bf16* __restrict__ Qb, const bf16* __restrict__ Kb,
    const bf16* __restrict__ Vt, const float* __restrict__ rel,
    bf16* __restrict__ AO) {
  __shared__ float relc[2049];
  __shared__ bf16 pbuf[4][16][136];  // per-wave P tile, 272B stride (2-way = free)
  const int bh = blockIdx.y, qb0 = blockIdx.x * 64;
  const int h = bh & 15, b = bh >> 4;
  const int tid = threadIdx.x, w = tid >> 6, l = tid & 63;
  for (int i = tid; i < 2049; i += 256) relc[i] = rel[(size_t)i * 16 + h];
  __syncthreads();
  const int fr = l & 15, fq = l >> 4, lrow = fq * 4;
  const int q0 = qb0 + w * 16;
  const bf16* Qp = Qb + ((size_t)bh * 2048 + q0) * 64;
  short8 qf[2];
#pragma unroll
  for (int ks = 0; ks < 2; ++ks)
    qf[ks] = *(const short8*)(Qp + (size_t)fr * 64 + ks * 32 + fq * 8);
  float m2[4], ll[4];
  f32x4 oacc[4] = {};
#pragma unroll
  for (int r = 0; r < 4; ++r) { m2[r] = -1e30f; ll[r] = 0.f; }
  const bf16* Kbh = Kb + (size_t)bh * 2048 * 64;
  const bf16* Vbh = Vt + (size_t)bh * 64 * 2048;
  const f32x4 vzero = {0.f, 0.f, 0.f, 0.f};

  for (int kt = 0; kt < 2048; kt += 128) {
    // ---- S = Q K^T  (16 q x 128 kv), K frags straight from global (L2-hot)
    f32x4 s[8];
#pragma unroll
    for (int ni = 0; ni < 8; ++ni) {
      s[ni] = vzero;
#pragma unroll
      for (int ks = 0; ks < 2; ++ks) {
        short8 kf = *(const short8*)(Kbh + (size_t)(kt + ni * 16 + fr) * 64 +
                                     ks * 32 + fq * 8);
        s[ni] = mfma16(qf[ks], kf, s[ni]);
      }
    }
    // ---- scale + relative bias, row-max (log2 domain)
    float mx[4] = {-1e30f, -1e30f, -1e30f, -1e30f};
#pragma unroll
    for (int ni = 0; ni < 8; ++ni)
#pragma unroll
      for (int r = 0; r < 4; ++r) {
        int j = kt + ni * 16 + fr;
        int i = q0 + lrow + r;
        int dd = j - i;
        dd = dd < -1024 ? -1024 : (dd > 1024 ? 1024 : dd);
        float sv = (s[ni][r] * 0.125f + relc[dd + 1024]) * 1.44269504f;
        s[ni][r] = sv;
        mx[r] = fmaxf(mx[r], sv);
      }
#pragma unroll
    for (int xm = 1; xm <= 8; xm <<= 1)
#pragma unroll
      for (int r = 0; r < 4; ++r)
        mx[r] = fmaxf(mx[r], __shfl_xor(mx[r], xm));
    float fac[4], rs[4] = {0.f, 0.f, 0.f, 0.f};
#pragma unroll
    for (int r = 0; r < 4; ++r) {
      float nm = fmaxf(m2[r], mx[r]);
      fac[r] = exp2f(m2[r] - nm);
      m2[r] = nm;
    }
#pragma unroll
    for (int ni = 0; ni < 8; ++ni)
#pragma unroll
      for (int r = 0; r < 4; ++r) {
        float p = exp2f(s[ni][r] - m2[r]);
        s[ni][r] = p;
        rs[r] += p;
      }
#pragma unroll
    for (int xm = 1; xm <= 8; xm <<= 1)
#pragma unroll
      for (int r = 0; r < 4; ++r) rs[r] += __shfl_xor(rs[r], xm);
#pragma unroll
    for (int r = 0; r < 4; ++r) ll[r] = ll[r] * fac[r] + rs[r];
#pragma unroll
    for (int nd = 0; nd < 4; ++nd)
#pragma unroll
      for (int r = 0; r < 4; ++r) oacc[nd][r] *= fac[r];
    // ---- P -> wave-private LDS (layout swap for A-fragment)
#pragma unroll
    for (int ni = 0; ni < 8; ++ni)
#pragma unroll
      for (int r = 0; r < 4; ++r)
        pbuf[w][lrow + r][ni * 16 + fr] = __float2bfloat16(s[ni][r]);
    // ---- O += P V, V frags straight from global (transposed layout)
#pragma unroll
    for (int ks = 0; ks < 4; ++ks) {
      short8 pf = *(const short8*)&pbuf[w][fr][ks * 32 + fq * 8];
#pragma unroll
      for (int nd = 0; nd < 4; ++nd) {
        short8 vf = *(const short8*)(Vbh + (size_t)(nd * 16 + fr) * 2048 + kt +
                                     ks * 32 + fq * 8);
        oacc[nd] = mfma16(pf, vf, oacc[nd]);
      }
    }
  }
  float rin[4];
#pragma unroll
  for (int r = 0; r < 4; ++r) rin[r] = 1.f / ll[r];
#pragma unroll
  for (int nd = 0; nd < 4; ++nd)
#pragma unroll
    for (int r = 0; r < 4; ++r) {
      int t = q0 + lrow + r;
      int dc = nd * 16 + fr;
      AO[((size_t)b * 2048 + t) * 1024 + h * 64 + dc] =
          __float2bfloat16(oacc[nd][r] * rin[r]);
    }
}

// ---------------------------------------------------------------------------
extern "C" void kernel_launch(void* const* d_in, const int* in_sizes, int n_in,
                              void* d_out, int out_size, void* d_ws,
                              size_t ws_size, hipStream_t stream) {
  const float* x = (const float*)d_in[0];     // [2,2048,1024]
  const float* Wqkv = (const float*)d_in[1];  // [3072,1024]
  const float* Wout = (const float*)d_in[2];  // [1024,1024]
  const float* bout = (const float*)d_in[3];  // [1024]
  const float* rel = (const float*)d_in[4];   // [2049,16]
  float* out = (float*)d_out;

  char* p = (char*)d_ws;
  bf16* xb  = (bf16*)(p);                      // 8 MB  [4096][1024]
  bf16* wqb = (bf16*)(p + (8ull << 20));       // 6 MB  [3072][1024]
  bf16* wob = (bf16*)(p + (14ull << 20));      // 2 MB  [1024][1024]
  bf16* Qb  = (bf16*)(p + (16ull << 20));      // 8 MB  [32][2048][64]
  bf16* Kb  = (bf16*)(p + (24ull << 20));      // 8 MB
  bf16* Vb  = (bf16*)(p + (32ull << 20));      // 8 MB
  bf16* Vt  = (bf16*)(p + (40ull << 20));      // 8 MB  [32][64][2048]
  bf16* aob = (bf16*)(p + (48ull << 20));      // 8 MB  [4096][1024]

  k_cvt<<<4096, 256, 0, stream>>>(x, xb);
  k_cvt<<<3072, 256, 0, stream>>>(Wqkv, wqb);
  k_cvt<<<1024, 256, 0, stream>>>(Wout, wob);
  k_gemm<<<dim3(32, 24), 256, 0, stream>>>(xb, wqb, 4096, 3072, 1024, 0,
                                           Qb, Kb, Vb, nullptr, nullptr);
  k_trv<<<dim3(32, 32), 256, 0, stream>>>(Vb, Vt);
  k_attn<<<dim3(32, 32), 256, 0, stream>>>(Qb, Kb, Vt, rel, aob);
  k_gemm<<<dim3(32, 8), 256, 0, stream>>>(aob, wob, 4096, 1024, 1024, 1,
                                          nullptr, nullptr, nullptr, out, bout);
}

// Round 2
// 213.380 us; speedup vs baseline: 1.9943x; 1.9943x over previous
//
#include <hip/hip_runtime.h>
#include <hip/hip_bf16.h>

typedef __attribute__((ext_vector_type(8))) short short8;
typedef __attribute__((ext_vector_type(4))) float f32x4;
typedef __attribute__((ext_vector_type(4))) unsigned short u16x4;
typedef __hip_bfloat16 bf16;

#define GLD_LDS16(g, l) __builtin_amdgcn_global_load_lds(                      \
    (const __attribute__((address_space(1))) void*)(g),                        \
    (__attribute__((address_space(3))) void*)(l), 16, 0, 0)

static __device__ __forceinline__ f32x4 mfma16(short8 a, short8 b, f32x4 c) {
  return __builtin_amdgcn_mfma_f32_16x16x32_bf16(a, b, c, 0, 0, 0);
}

// ---------------- fp32 -> bf16 convert (vectorized, exact-grid) -------------
__global__ __launch_bounds__(256) void k_cvt(const float* __restrict__ in,
                                             bf16* __restrict__ out) {
  long i = (long)blockIdx.x * 256 + threadIdx.x;
  f32x4 v = *(const f32x4*)(in + i * 4);
  u16x4 o;
#pragma unroll
  for (int j = 0; j < 4; ++j)
    o[j] = __builtin_bit_cast(unsigned short, __float2bfloat16(v[j]));
  *(u16x4*)((unsigned short*)out + i * 4) = o;
}

// ---------------- 128x128 bf16 GEMM, B stored [N][K] (K-major) --------------
// epi==0: scatter into Q/K/V  [bh][2048][64]
// epi==1: fp32 out[t*N+e] = acc + bias[e]
__global__ __launch_bounds__(256) void k_gemm(
    const bf16* __restrict__ A, const bf16* __restrict__ B,
    int M, int N, int K, int epi,
    bf16* __restrict__ Qb, bf16* __restrict__ Kb, bf16* __restrict__ Vb,
    float* __restrict__ Out, const float* __restrict__ bias) {
  __shared__ bf16 lA[4096];  // 128 x 32
  __shared__ bf16 lB[4096];  // 128 x 32
  const int tid = threadIdx.x, w = tid >> 6, l = tid & 63;
  const int m0 = blockIdx.x * 128, n0 = blockIdx.y * 128;
  const int wrow = (w >> 1) * 64, wcol = (w & 1) * 64;
  const int fr = l & 15, fq = l >> 4;
  f32x4 acc[4][4] = {};
  const int c0 = w * 64 + l, c1 = c0 + 256;  // 16B chunk ids
  const bf16* Ag0 = A + (size_t)(m0 + (c0 >> 2)) * K + (c0 & 3) * 8;
  const bf16* Ag1 = A + (size_t)(m0 + (c1 >> 2)) * K + (c1 & 3) * 8;
  const bf16* Bg0 = B + (size_t)(n0 + (c0 >> 2)) * K + (c0 & 3) * 8;
  const bf16* Bg1 = B + (size_t)(n0 + (c1 >> 2)) * K + (c1 & 3) * 8;
  bf16* lA0 = &lA[w * 512];
  bf16* lA1 = &lA[2048 + w * 512];
  bf16* lB0 = &lB[w * 512];
  bf16* lB1 = &lB[2048 + w * 512];

  for (int k0 = 0; k0 < K; k0 += 32) {
    __syncthreads();  // previous compute done before overwrite
    GLD_LDS16(Ag0 + k0, lA0);
    GLD_LDS16(Ag1 + k0, lA1);
    GLD_LDS16(Bg0 + k0, lB0);
    GLD_LDS16(Bg1 + k0, lB1);
    __syncthreads();  // drains vmcnt -> staged data visible
    short8 af[4], bfv[4];
#pragma unroll
    for (int mi = 0; mi < 4; ++mi)
      af[mi] = *(const short8*)&lA[(wrow + mi * 16 + fr) * 32 + fq * 8];
#pragma unroll
    for (int ni = 0; ni < 4; ++ni)
      bfv[ni] = *(const short8*)&lB[(wcol + ni * 16 + fr) * 32 + fq * 8];
#pragma unroll
    for (int mi = 0; mi < 4; ++mi)
#pragma unroll
      for (int ni = 0; ni < 4; ++ni)
        acc[mi][ni] = mfma16(af[mi], bfv[ni], acc[mi][ni]);
  }

  const int lrow = fq * 4;
  if (epi == 0) {
#pragma unroll
    for (int mi = 0; mi < 4; ++mi)
#pragma unroll
      for (int ni = 0; ni < 4; ++ni)
#pragma unroll
        for (int r = 0; r < 4; ++r) {
          int t = m0 + wrow + mi * 16 + lrow + r;
          int e = n0 + wcol + ni * 16 + fr;
          int sect = e >> 10, eh = (e >> 6) & 15, dh = e & 63;
          int b = t >> 11, tt = t & 2047;
          size_t idx = (((size_t)b * 16 + eh) * 2048 + tt) * 64 + dh;
          bf16 val = __float2bfloat16(acc[mi][ni][r]);
          if (sect == 0) Qb[idx] = val;
          else if (sect == 1) Kb[idx] = val;
          else Vb[idx] = val;
        }
  } else {
#pragma unroll
    for (int mi = 0; mi < 4; ++mi)
#pragma unroll
      for (int ni = 0; ni < 4; ++ni)
#pragma unroll
        for (int r = 0; r < 4; ++r) {
          int t = m0 + wrow + mi * 16 + lrow + r;
          int e = n0 + wcol + ni * 16 + fr;
          Out[(size_t)t * N + e] = acc[mi][ni][r] + bias[e];
        }
  }
}

// ---------------- V transpose: [bh][2048][64] -> [bh][64][2048] -------------
__global__ __launch_bounds__(256) void k_trv(const bf16* __restrict__ Vb,
                                             bf16* __restrict__ Vt) {
  __shared__ bf16 tile[64][80];  // 160B row stride, 16B aligned
  const int bh = blockIdx.y, t0 = blockIdx.x * 64;
  const int tid = threadIdx.x;
#pragma unroll
  for (int it = 0; it < 2; ++it) {
    int idx = tid + it * 256;
    int r = idx >> 3, c8 = (idx & 7) * 8;
    short8 v = *(const short8*)(Vb + ((size_t)bh * 2048 + t0 + r) * 64 + c8);
    *(short8*)&tile[r][c8] = v;
  }
  __syncthreads();
#pragma unroll
  for (int it = 0; it < 2; ++it) {
    int idx = tid + it * 256;
    int d = idx >> 3, c8 = (idx & 7) * 8;
    short8 o;
#pragma unroll
    for (int j = 0; j < 8; ++j)
      o[j] = __builtin_bit_cast(short, tile[c8 + j][d]);
    *(short8*)(Vt + ((size_t)bh * 64 + d) * 2048 + t0 + c8) = o;
  }
}

// ---------------- flash attention, LDS-staged double-buffered ---------------
// 512 threads = 8 waves, wave owns 16 q-rows -> block covers 128 q-rows.
// grid: 512 blocks (XCD-swizzled: xcd = id&7 owns bh in [xcd*4, xcd*4+4)).
// KV tile = 64 rows; K,V staged in LDS via global_load_lds, XOR-swizzled
// source (chunk ^= row&7) with linear LDS dest; read applies same XOR.
__global__ __launch_bounds__(512, 4) void k_attn(
    const bf16* __restrict__ Qb, const bf16* __restrict__ Kb,
    const bf16* __restrict__ Vt, const float* __restrict__ rel,
    bf16* __restrict__ AO) {
  __shared__ float relc[2052];
  __shared__ bf16 lK[2][64 * 64];
  __shared__ bf16 lV[2][64 * 64];
  __shared__ bf16 pbuf[8][16][72];  // per-wave P tile, 144B row stride

  const int id = blockIdx.x;          // 0..511
  const int xcd = id & 7, j = id >> 3;  // j: 0..63
  const int bh = xcd * 4 + (j >> 4), qt = j & 15;
  const int h = bh & 15, b = bh >> 4;
  const int tid = threadIdx.x, w = tid >> 6, l = tid & 63;
  const int fr = l & 15, fq = l >> 4, lrow = fq * 4;
  const int q0 = qt * 128 + w * 16;

  for (int i = tid; i < 2049; i += 512)
    relc[i] = rel[(size_t)i * 16 + h] * 1.44269504f;  // prescale by log2(e)

  const bf16* Kbh = Kb + (size_t)bh * 2048 * 64;
  const bf16* Vbh = Vt + (size_t)bh * 64 * 2048;
  // staging geometry: thread t handles 16B chunk (row = t>>3, c = t&7);
  // source chunk pre-swizzled: c ^ (row & 7); LDS dest linear (tid*16B).
  const int srow = tid >> 3, ssw = ((tid & 7) ^ (srow & 7)) * 8;
  const bf16* Ksrc = Kbh + (size_t)srow * 64 + ssw;
  const bf16* Vsrc = Vbh + (size_t)srow * 2048 + ssw;

  // Q fragments in registers
  const bf16* Qp = Qb + ((size_t)bh * 2048 + q0) * 64;
  short8 qf[2];
#pragma unroll
  for (int ks = 0; ks < 2; ++ks)
    qf[ks] = *(const short8*)(Qp + (size_t)fr * 64 + ks * 32 + fq * 8);

  float m2[4], ll[4];
  f32x4 oacc[4] = {};
#pragma unroll
  for (int r = 0; r < 4; ++r) { m2[r] = -1e30f; ll[r] = 0.f; }
  const f32x4 vzero = {0.f, 0.f, 0.f, 0.f};

  // prologue: stage tile 0
  GLD_LDS16(Ksrc, &lK[0][tid * 8]);
  GLD_LDS16(Vsrc, &lV[0][tid * 8]);
  __syncthreads();

  int cur = 0;
  for (int t = 0; t < 32; ++t) {
    const int kt = t * 64;
    if (t < 31) {  // issue next-tile stage; overlaps this tile's compute
      GLD_LDS16(Ksrc + (size_t)(kt + 64) * 64, &lK[cur ^ 1][tid * 8]);
      GLD_LDS16(Vsrc + (kt + 64), &lV[cur ^ 1][tid * 8]);
    }
    // ---- S = Q K^T  (16 q x 64 kv)
    f32x4 s[4];
#pragma unroll
    for (int ni = 0; ni < 4; ++ni) {
      s[ni] = vzero;
#pragma unroll
      for (int ks = 0; ks < 2; ++ks) {
        int row = ni * 16 + fr;
        int ch = (ks * 4 + fq) ^ (fr & 7);
        short8 kf = *(const short8*)&lK[cur][row * 64 + ch * 8];
        s[ni] = mfma16(qf[ks], kf, s[ni]);
      }
    }
    // ---- scale + relative bias (log2 domain), row-max
    float mx[4] = {-1e30f, -1e30f, -1e30f, -1e30f};
#pragma unroll
    for (int ni = 0; ni < 4; ++ni)
#pragma unroll
      for (int r = 0; r < 4; ++r) {
        int jj = kt + ni * 16 + fr;
        int ii = q0 + lrow + r;
        int dd = jj - ii;
        dd = dd < -1024 ? -1024 : (dd > 1024 ? 1024 : dd);
        float sv = fmaf(s[ni][r], 0.18033688f, relc[dd + 1024]);
        s[ni][r] = sv;
        mx[r] = fmaxf(mx[r], sv);
      }
#pragma unroll
    for (int xm = 1; xm <= 8; xm <<= 1)
#pragma unroll
      for (int r = 0; r < 4; ++r)
        mx[r] = fmaxf(mx[r], __shfl_xor(mx[r], xm));
    float fac[4], rs[4] = {0.f, 0.f, 0.f, 0.f};
#pragma unroll
    for (int r = 0; r < 4; ++r) {
      float nm = fmaxf(m2[r], mx[r]);
      fac[r] = exp2f(m2[r] - nm);
      m2[r] = nm;
    }
#pragma unroll
    for (int ni = 0; ni < 4; ++ni)
#pragma unroll
      for (int r = 0; r < 4; ++r) {
        float p = exp2f(s[ni][r] - m2[r]);
        s[ni][r] = p;
        rs[r] += p;
      }
#pragma unroll
    for (int xm = 1; xm <= 8; xm <<= 1)
#pragma unroll
      for (int r = 0; r < 4; ++r) rs[r] += __shfl_xor(rs[r], xm);
#pragma unroll
    for (int r = 0; r < 4; ++r) ll[r] = ll[r] * fac[r] + rs[r];
#pragma unroll
    for (int nd = 0; nd < 4; ++nd)
#pragma unroll
      for (int r = 0; r < 4; ++r) oacc[nd][r] *= fac[r];
    // ---- P -> wave-private LDS (layout swap for A-fragment)
#pragma unroll
    for (int ni = 0; ni < 4; ++ni)
#pragma unroll
      for (int r = 0; r < 4; ++r)
        pbuf[w][lrow + r][ni * 16 + fr] = __float2bfloat16(s[ni][r]);
    // ---- O += P V (V from swizzled LDS)
#pragma unroll
    for (int ks = 0; ks < 2; ++ks) {
      short8 pf = *(const short8*)&pbuf[w][fr][ks * 32 + fq * 8];
#pragma unroll
      for (int nd = 0; nd < 4; ++nd) {
        int row = nd * 16 + fr;
        int ch = (ks * 4 + fq) ^ (fr & 7);
        short8 vf = *(const short8*)&lV[cur][row * 64 + ch * 8];
        oacc[nd] = mfma16(pf, vf, oacc[nd]);
      }
    }
    if (t < 31) __syncthreads();  // drains vmcnt: next tile staged & buffers free
    cur ^= 1;
  }

  float rin[4];
#pragma unroll
  for (int r = 0; r < 4; ++r) rin[r] = 1.f / ll[r];
#pragma unroll
  for (int nd = 0; nd < 4; ++nd)
#pragma unroll
    for (int r = 0; r < 4; ++r) {
      int t = q0 + lrow + r;
      int dc = nd * 16 + fr;
      AO[((size_t)b * 2048 + t) * 1024 + h * 64 + dc] =
          __float2bfloat16(oacc[nd][r] * rin[r]);
    }
}

// ---------------------------------------------------------------------------
extern "C" void kernel_launch(void* const* d_in, const int* in_sizes, int n_in,
                              void* d_out, int out_size, void* d_ws,
                              size_t ws_size, hipStream_t stream) {
  const float* x = (const float*)d_in[0];     // [2,2048,1024]
  const float* Wqkv = (const float*)d_in[1];  // [3072,1024]
  const float* Wout = (const float*)d_in[2];  // [1024,1024]
  const float* bout = (const float*)d_in[3];  // [1024]
  const float* rel = (const float*)d_in[4];   // [2049,16]
  float* out = (float*)d_out;

  char* p = (char*)d_ws;
  bf16* xb  = (bf16*)(p);                      // 8 MB  [4096][1024]
  bf16* wqb = (bf16*)(p + (8ull << 20));       // 6 MB  [3072][1024]
  bf16* wob = (bf16*)(p + (14ull << 20));      // 2 MB  [1024][1024]
  bf16* Qb  = (bf16*)(p + (16ull << 20));      // 8 MB  [32][2048][64]
  bf16* Kb  = (bf16*)(p + (24ull << 20));      // 8 MB
  bf16* Vb  = (bf16*)(p + (32ull << 20));      // 8 MB
  bf16* Vt  = (bf16*)(p + (40ull << 20));      // 8 MB  [32][64][2048]
  bf16* aob = (bf16*)(p + (48ull << 20));      // 8 MB  [4096][1024]

  k_cvt<<<4096, 256, 0, stream>>>(x, xb);
  k_cvt<<<3072, 256, 0, stream>>>(Wqkv, wqb);
  k_cvt<<<1024, 256, 0, stream>>>(Wout, wob);
  k_gemm<<<dim3(32, 24), 256, 0, stream>>>(xb, wqb, 4096, 3072, 1024, 0,
                                           Qb, Kb, Vb, nullptr, nullptr);
  k_trv<<<dim3(32, 32), 256, 0, stream>>>(Vb, Vt);
  k_attn<<<512, 512, 0, stream>>>(Qb, Kb, Vt, rel, aob);
  k_gemm<<<dim3(32, 8), 256, 0, stream>>>(aob, wob, 4096, 1024, 1024, 1,
                                          nullptr, nullptr, nullptr, out, bout);
}

// Round 3
// 185.522 us; speedup vs baseline: 2.2938x; 1.1502x over previous
//
#include <hip/hip_runtime.h>
#include <hip/hip_bf16.h>

typedef __attribute__((ext_vector_type(8))) short short8;
typedef __attribute__((ext_vector_type(4))) float f32x4;
typedef __attribute__((ext_vector_type(4))) unsigned short u16x4;
typedef __attribute__((ext_vector_type(2))) unsigned int u32x2;
typedef __hip_bfloat16 bf16;

#define GLD_LDS16(g, l) __builtin_amdgcn_global_load_lds(                      \
    (const __attribute__((address_space(1))) void*)(g),                        \
    (__attribute__((address_space(3))) void*)(l), 16, 0, 0)

static __device__ __forceinline__ f32x4 mfma16(short8 a, short8 b, f32x4 c) {
  return __builtin_amdgcn_mfma_f32_16x16x32_bf16(a, b, c, 0, 0, 0);
}

static __device__ __forceinline__ unsigned pk2(float a, float b) {
  unsigned short x = __builtin_bit_cast(unsigned short, __float2bfloat16(a));
  unsigned short y = __builtin_bit_cast(unsigned short, __float2bfloat16(b));
  return (unsigned)x | ((unsigned)y << 16);
}

// ---------------- fp32 -> bf16 convert (vectorized, exact-grid) -------------
__global__ __launch_bounds__(256) void k_cvt(const float* __restrict__ in,
                                             bf16* __restrict__ out) {
  long i = (long)blockIdx.x * 256 + threadIdx.x;
  f32x4 v = *(const f32x4*)(in + i * 4);
  u16x4 o;
#pragma unroll
  for (int j = 0; j < 4; ++j)
    o[j] = __builtin_bit_cast(unsigned short, __float2bfloat16(v[j]));
  *(u16x4*)((unsigned short*)out + i * 4) = o;
}

// ---------------- per-head bias table, clamp baked, log2e prescaled ---------
// relp[h][i] = bf16( rel[clamp(i-2047,±1024)+1024][h] * log2(e) ),  i in [0,4096)
__global__ __launch_bounds__(256) void k_bias(const float* __restrict__ rel,
                                              bf16* __restrict__ relp) {
  int i = blockIdx.x * 256 + threadIdx.x;  // 0..65535
  int h = i >> 12, ii = i & 4095;
  int dd = ii - 2047;
  dd = dd < -1024 ? -1024 : (dd > 1024 ? 1024 : dd);
  relp[i] = __float2bfloat16(rel[(size_t)(dd + 1024) * 16 + h] * 1.44269504f);
}

// ---------------- 128x128 bf16 GEMM, B stored [N][K] (K-major) --------------
__global__ __launch_bounds__(256) void k_gemm(
    const bf16* __restrict__ A, const bf16* __restrict__ B,
    int M, int N, int K, int epi,
    bf16* __restrict__ Qb, bf16* __restrict__ Kb, bf16* __restrict__ Vb,
    float* __restrict__ Out, const float* __restrict__ bias) {
  __shared__ bf16 lA[4096];  // 128 x 32
  __shared__ bf16 lB[4096];  // 128 x 32
  const int tid = threadIdx.x, w = tid >> 6, l = tid & 63;
  const int m0 = blockIdx.x * 128, n0 = blockIdx.y * 128;
  const int wrow = (w >> 1) * 64, wcol = (w & 1) * 64;
  const int fr = l & 15, fq = l >> 4;
  f32x4 acc[4][4] = {};
  const int c0 = w * 64 + l, c1 = c0 + 256;  // 16B chunk ids
  const bf16* Ag0 = A + (size_t)(m0 + (c0 >> 2)) * K + (c0 & 3) * 8;
  const bf16* Ag1 = A + (size_t)(m0 + (c1 >> 2)) * K + (c1 & 3) * 8;
  const bf16* Bg0 = B + (size_t)(n0 + (c0 >> 2)) * K + (c0 & 3) * 8;
  const bf16* Bg1 = B + (size_t)(n0 + (c1 >> 2)) * K + (c1 & 3) * 8;
  bf16* lA0 = &lA[w * 512];
  bf16* lA1 = &lA[2048 + w * 512];
  bf16* lB0 = &lB[w * 512];
  bf16* lB1 = &lB[2048 + w * 512];

  for (int k0 = 0; k0 < K; k0 += 32) {
    __syncthreads();
    GLD_LDS16(Ag0 + k0, lA0);
    GLD_LDS16(Ag1 + k0, lA1);
    GLD_LDS16(Bg0 + k0, lB0);
    GLD_LDS16(Bg1 + k0, lB1);
    __syncthreads();
    short8 af[4], bfv[4];
#pragma unroll
    for (int mi = 0; mi < 4; ++mi)
      af[mi] = *(const short8*)&lA[(wrow + mi * 16 + fr) * 32 + fq * 8];
#pragma unroll
    for (int ni = 0; ni < 4; ++ni)
      bfv[ni] = *(const short8*)&lB[(wcol + ni * 16 + fr) * 32 + fq * 8];
#pragma unroll
    for (int mi = 0; mi < 4; ++mi)
#pragma unroll
      for (int ni = 0; ni < 4; ++ni)
        acc[mi][ni] = mfma16(af[mi], bfv[ni], acc[mi][ni]);
  }

  const int lrow = fq * 4;
  if (epi == 0) {
#pragma unroll
    for (int mi = 0; mi < 4; ++mi)
#pragma unroll
      for (int ni = 0; ni < 4; ++ni)
#pragma unroll
        for (int r = 0; r < 4; ++r) {
          int t = m0 + wrow + mi * 16 + lrow + r;
          int e = n0 + wcol + ni * 16 + fr;
          int sect = e >> 10, eh = (e >> 6) & 15, dh = e & 63;
          int b = t >> 11, tt = t & 2047;
          size_t idx = (((size_t)b * 16 + eh) * 2048 + tt) * 64 + dh;
          bf16 val = __float2bfloat16(acc[mi][ni][r]);
          if (sect == 0) Qb[idx] = val;
          else if (sect == 1) Kb[idx] = val;
          else Vb[idx] = val;
        }
  } else {
#pragma unroll
    for (int mi = 0; mi < 4; ++mi)
#pragma unroll
      for (int ni = 0; ni < 4; ++ni)
#pragma unroll
        for (int r = 0; r < 4; ++r) {
          int t = m0 + wrow + mi * 16 + lrow + r;
          int e = n0 + wcol + ni * 16 + fr;
          Out[(size_t)t * N + e] = acc[mi][ni][r] + bias[e];
        }
  }
}

// ---------------- V transpose: [bh][2048][64] -> [bh][64][2048] -------------
__global__ __launch_bounds__(256) void k_trv(const bf16* __restrict__ Vb,
                                             bf16* __restrict__ Vt) {
  __shared__ bf16 tile[64][80];
  const int bh = blockIdx.y, t0 = blockIdx.x * 64;
  const int tid = threadIdx.x;
#pragma unroll
  for (int it = 0; it < 2; ++it) {
    int idx = tid + it * 256;
    int r = idx >> 3, c8 = (idx & 7) * 8;
    short8 v = *(const short8*)(Vb + ((size_t)bh * 2048 + t0 + r) * 64 + c8);
    *(short8*)&tile[r][c8] = v;
  }
  __syncthreads();
#pragma unroll
  for (int it = 0; it < 2; ++it) {
    int idx = tid + it * 256;
    int d = idx >> 3, c8 = (idx & 7) * 8;
    short8 o;
#pragma unroll
    for (int j = 0; j < 8; ++j)
      o[j] = __builtin_bit_cast(short, tile[c8 + j][d]);
    *(short8*)(Vt + ((size_t)bh * 64 + d) * 2048 + t0 + c8) = o;
  }
}

// ---------------- flash attention, swapped-QK^T lane-local softmax ----------
// 512 thr = 8 waves, wave owns 16 q-rows. Swapped mfma(K,Q) -> lane holds one
// q-row's 16 scores; softmax reduces in-register + 2 shuffles. Bias from a
// global per-head clamp-baked bf16 table (VMEM pipe). P packed via b64 writes
// into a swizzled wave-private pbuf read back as the B-frag of O^T = V^T P^T.
__global__ __launch_bounds__(512, 4) void k_attn(
    const bf16* __restrict__ Qb, const bf16* __restrict__ Kb,
    const bf16* __restrict__ Vt, const bf16* __restrict__ relp,
    bf16* __restrict__ AO) {
  __shared__ bf16 lK[2][4096];
  __shared__ bf16 lV[2][4096];
  __shared__ bf16 pbuf[8][1024];  // per-wave 16q x 64kv, chunk-swizzled

  const int id = blockIdx.x;            // 0..511
  const int xcd = id & 7, j = id >> 3;  // j: 0..63
  const int bh = xcd * 4 + (j >> 4), qt = j & 15;
  const int h = bh & 15, b = bh >> 4;
  const int tid = threadIdx.x, w = tid >> 6, l = tid & 63;
  const int fr = l & 15, fq = l >> 4;
  const int q0 = qt * 128 + w * 16;

  const bf16* Kbh = Kb + (size_t)bh * 2048 * 64;
  const bf16* Vbh = Vt + (size_t)bh * 64 * 2048;
  const int srow = tid >> 3, ssw = ((tid & 7) ^ (srow & 7)) * 8;
  const bf16* Ksrc = Kbh + (size_t)srow * 64 + ssw;
  const bf16* Vsrc = Vbh + (size_t)srow * 2048 + ssw;

  // Q fragment: Q[q=fr][d = ks*32 + fq*8 + j]
  const bf16* Qp = Qb + ((size_t)bh * 2048 + q0) * 64;
  short8 qf[2];
#pragma unroll
  for (int ks = 0; ks < 2; ++ks)
    qf[ks] = *(const short8*)(Qp + (size_t)fr * 64 + ks * 32 + fq * 8);

  // bias table base: idx = kt + 16ni + r + (fq*4 - fr - q0 + 2047), in [0,4095)
  const unsigned short* bpu =
      (const unsigned short*)relp + h * 4096 + (fq * 4 - fr - q0 + 2047);

  float m2 = -3e38f, ll = 0.f;
  f32x4 oacc[4] = {};
  const f32x4 vzero = {0.f, 0.f, 0.f, 0.f};
  char* pb = (char*)&pbuf[w][0];
  const int frs = fr & 7;

  GLD_LDS16(Ksrc, &lK[0][tid * 8]);
  GLD_LDS16(Vsrc, &lV[0][tid * 8]);
  __syncthreads();

  int cur = 0;
  for (int t = 0; t < 32; ++t) {
    const int kt = t * 64;
    if (t < 31) {  // next-tile stage overlaps this tile's compute
      GLD_LDS16(Ksrc + (size_t)(kt + 64) * 64, &lK[cur ^ 1][tid * 8]);
      GLD_LDS16(Vsrc + (kt + 64), &lV[cur ^ 1][tid * 8]);
    }
    // ---- bias prefetch (VMEM, L2-hot, coalesced)
    unsigned short bu[4][4];
#pragma unroll
    for (int ni = 0; ni < 4; ++ni)
#pragma unroll
      for (int r = 0; r < 4; ++r) bu[ni][r] = bpu[kt + ni * 16 + r];
    // ---- S^T = K Q^T : lane gets S[q=fr][kv = kt + 16ni + fq*4 + r]
    f32x4 s[4];
#pragma unroll
    for (int ni = 0; ni < 4; ++ni) {
      s[ni] = vzero;
#pragma unroll
      for (int ks = 0; ks < 2; ++ks) {
        short8 kf = *(const short8*)&lK[cur][(ni * 16 + fr) * 64 +
                                            (((ks * 4 + fq) ^ frs) * 8)];
        s[ni] = mfma16(kf, qf[ks], s[ni]);
      }
    }
    // ---- scale + bias (log2 domain), lane-local row max
    float mx = -3e38f;
#pragma unroll
    for (int ni = 0; ni < 4; ++ni)
#pragma unroll
      for (int r = 0; r < 4; ++r) {
        float bias = __builtin_bit_cast(float, (unsigned)bu[ni][r] << 16);
        float sv = fmaf(s[ni][r], 0.18033688f, bias);
        s[ni][r] = sv;
        mx = fmaxf(mx, sv);
      }
    mx = fmaxf(mx, __shfl_xor(mx, 16));
    mx = fmaxf(mx, __shfl_xor(mx, 32));
    if (__any(mx > m2)) {  // rescale only when the running max grows
      float nm = fmaxf(m2, mx);
      float fac = exp2f(m2 - nm);
      m2 = nm;
      ll *= fac;
#pragma unroll
      for (int nd = 0; nd < 4; ++nd)
#pragma unroll
        for (int r = 0; r < 4; ++r) oacc[nd][r] *= fac;
    }
    float rs = 0.f;
#pragma unroll
    for (int ni = 0; ni < 4; ++ni) {
#pragma unroll
      for (int r = 0; r < 4; ++r) {
        float p = exp2f(s[ni][r] - m2);
        s[ni][r] = p;
        rs += p;
      }
    }
    rs += __shfl_xor(rs, 16);
    rs += __shfl_xor(rs, 32);
    ll += rs;
    // ---- pack P row-chunk (4 contiguous kv) and b64-write to swizzled pbuf
#pragma unroll
    for (int ni = 0; ni < 4; ++ni) {
      u32x2 wv;
      wv[0] = pk2(s[ni][0], s[ni][1]);
      wv[1] = pk2(s[ni][2], s[ni][3]);
      int off = fr * 128 + (((2 * ni + (fq >> 1)) ^ frs) * 16) + (fq & 1) * 8;
      *(u32x2*)(pb + off) = wv;
    }
    // ---- O^T += V^T P^T
#pragma unroll
    for (int ks = 0; ks < 2; ++ks) {
      short8 pf = *(const short8*)(pb + fr * 128 + (((ks * 4 + fq) ^ frs) * 16));
#pragma unroll
      for (int nd = 0; nd < 4; ++nd) {
        short8 vf = *(const short8*)&lV[cur][(nd * 16 + fr) * 64 +
                                            (((ks * 4 + fq) ^ frs) * 8)];
        oacc[nd] = mfma16(vf, pf, oacc[nd]);
      }
    }
    if (t < 31) __syncthreads();
    cur ^= 1;
  }

  // lane holds O^T[d = 16nd + fq*4 + r][q = fr]; packed 8B stores
  float rin = 1.f / ll;
  bf16* aor = AO + ((size_t)(b * 2048 + q0 + fr)) * 1024 + h * 64 + fq * 4;
#pragma unroll
  for (int nd = 0; nd < 4; ++nd) {
    u32x2 ov;
    ov[0] = pk2(oacc[nd][0] * rin, oacc[nd][1] * rin);
    ov[1] = pk2(oacc[nd][2] * rin, oacc[nd][3] * rin);
    *(u32x2*)(aor + nd * 16) = ov;
  }
}

// ---------------------------------------------------------------------------
extern "C" void kernel_launch(void* const* d_in, const int* in_sizes, int n_in,
                              void* d_out, int out_size, void* d_ws,
                              size_t ws_size, hipStream_t stream) {
  const float* x = (const float*)d_in[0];     // [2,2048,1024]
  const float* Wqkv = (const float*)d_in[1];  // [3072,1024]
  const float* Wout = (const float*)d_in[2];  // [1024,1024]
  const float* bout = (const float*)d_in[3];  // [1024]
  const float* rel = (const float*)d_in[4];   // [2049,16]
  float* out = (float*)d_out;

  char* p = (char*)d_ws;
  bf16* xb  = (bf16*)(p);                      // 8 MB  [4096][1024]
  bf16* wqb = (bf16*)(p + (8ull << 20));       // 6 MB  [3072][1024]
  bf16* wob = (bf16*)(p + (14ull << 20));      // 2 MB  [1024][1024]
  bf16* Qb  = (bf16*)(p + (16ull << 20));      // 8 MB  [32][2048][64]
  bf16* Kb  = (bf16*)(p + (24ull << 20));      // 8 MB
  bf16* Vb  = (bf16*)(p + (32ull << 20));      // 8 MB
  bf16* Vt  = (bf16*)(p + (40ull << 20));      // 8 MB  [32][64][2048]
  bf16* aob = (bf16*)(p + (48ull << 20));      // 8 MB  [4096][1024]
  bf16* relp = (bf16*)(p + (56ull << 20));     // 128 KB [16][4096]

  k_cvt<<<4096, 256, 0, stream>>>(x, xb);
  k_cvt<<<3072, 256, 0, stream>>>(Wqkv, wqb);
  k_cvt<<<1024, 256, 0, stream>>>(Wout, wob);
  k_bias<<<256, 256, 0, stream>>>(rel, relp);
  k_gemm<<<dim3(32, 24), 256, 0, stream>>>(xb, wqb, 4096, 3072, 1024, 0,
                                           Qb, Kb, Vb, nullptr, nullptr);
  k_trv<<<dim3(32, 32), 256, 0, stream>>>(Vb, Vt);
  k_attn<<<512, 512, 0, stream>>>(Qb, Kb, Vt, relp, aob);
  k_gemm<<<dim3(32, 8), 256, 0, stream>>>(aob, wob, 4096, 1024, 1024, 1,
                                          nullptr, nullptr, nullptr, out, bout);
}

// Round 5
// 177.439 us; speedup vs baseline: 2.3983x; 1.0456x over previous
//
#include <hip/hip_runtime.h>
#include <hip/hip_bf16.h>

typedef __attribute__((ext_vector_type(8))) short short8;
typedef __attribute__((ext_vector_type(4))) float f32x4;
typedef __attribute__((ext_vector_type(16))) float f32x16;
typedef __attribute__((ext_vector_type(4))) unsigned short u16x4;
typedef __attribute__((ext_vector_type(2))) unsigned int u32x2;
typedef __attribute__((ext_vector_type(4))) unsigned int u32x4;
typedef __hip_bfloat16 bf16;

#define GLD_LDS16(g, l) __builtin_amdgcn_global_load_lds(                      \
    (const __attribute__((address_space(1))) void*)(g),                        \
    (__attribute__((address_space(3))) void*)(l), 16, 0, 0)

static __device__ __forceinline__ f32x4 mfma16(short8 a, short8 b, f32x4 c) {
  return __builtin_amdgcn_mfma_f32_16x16x32_bf16(a, b, c, 0, 0, 0);
}
static __device__ __forceinline__ f32x16 mfma32(short8 a, short8 b, f32x16 c) {
  return __builtin_amdgcn_mfma_f32_32x32x16_bf16(a, b, c, 0, 0, 0);
}

static __device__ __forceinline__ unsigned pk2(float a, float b) {
  unsigned short x = __builtin_bit_cast(unsigned short, __float2bfloat16(a));
  unsigned short y = __builtin_bit_cast(unsigned short, __float2bfloat16(b));
  return (unsigned)x | ((unsigned)y << 16);
}

// vdst upper 32 lanes <-> vsrc lower 32 lanes. ONLY use with operands that
// hold DISTINCT values (identical-copy operands can be register-coalesced by
// the allocator -> self-swap bug; scalar reductions use __shfl_xor instead).
#define PLSWAP(a, b) asm("v_permlane32_swap_b32 %0, %1" : "+v"(a), "+v"(b))

// ---------------- fp32 -> bf16 convert (vectorized, exact-grid) -------------
__global__ __launch_bounds__(256) void k_cvt(const float* __restrict__ in,
                                             bf16* __restrict__ out) {
  long i = (long)blockIdx.x * 256 + threadIdx.x;
  f32x4 v = *(const f32x4*)(in + i * 4);
  u16x4 o;
#pragma unroll
  for (int j = 0; j < 4; ++j)
    o[j] = __builtin_bit_cast(unsigned short, __float2bfloat16(v[j]));
  *(u16x4*)((unsigned short*)out + i * 4) = o;
}

// ---------------- per-head bias table, clamp baked, log2e prescaled, f32 ----
// relpf[h][i] = rel[clamp(i-2047,±1024)+1024][h] * log2(e),  i in [0,4096)
__global__ __launch_bounds__(256) void k_bias(const float* __restrict__ rel,
                                              float* __restrict__ relpf) {
  int i = blockIdx.x * 256 + threadIdx.x;  // 0..65535
  int h = i >> 12, ii = i & 4095;
  int dd = ii - 2047;
  dd = dd < -1024 ? -1024 : (dd > 1024 ? 1024 : dd);
  relpf[i] = rel[(size_t)(dd + 1024) * 16 + h] * 1.44269504f;
}

// ---------------- 128x128 bf16 GEMM, B stored [N][K] (K-major) --------------
__global__ __launch_bounds__(256) void k_gemm(
    const bf16* __restrict__ A, const bf16* __restrict__ B,
    int M, int N, int K, int epi,
    bf16* __restrict__ Qb, bf16* __restrict__ Kb, bf16* __restrict__ Vb,
    float* __restrict__ Out, const float* __restrict__ bias) {
  __shared__ bf16 lA[4096];  // 128 x 32
  __shared__ bf16 lB[4096];  // 128 x 32
  const int tid = threadIdx.x, w = tid >> 6, l = tid & 63;
  const int m0 = blockIdx.x * 128, n0 = blockIdx.y * 128;
  const int wrow = (w >> 1) * 64, wcol = (w & 1) * 64;
  const int fr = l & 15, fq = l >> 4;
  f32x4 acc[4][4] = {};
  const int c0 = w * 64 + l, c1 = c0 + 256;  // 16B chunk ids
  const bf16* Ag0 = A + (size_t)(m0 + (c0 >> 2)) * K + (c0 & 3) * 8;
  const bf16* Ag1 = A + (size_t)(m0 + (c1 >> 2)) * K + (c1 & 3) * 8;
  const bf16* Bg0 = B + (size_t)(n0 + (c0 >> 2)) * K + (c0 & 3) * 8;
  const bf16* Bg1 = B + (size_t)(n0 + (c1 >> 2)) * K + (c1 & 3) * 8;
  bf16* lA0 = &lA[w * 512];
  bf16* lA1 = &lA[2048 + w * 512];
  bf16* lB0 = &lB[w * 512];
  bf16* lB1 = &lB[2048 + w * 512];

  for (int k0 = 0; k0 < K; k0 += 32) {
    __syncthreads();
    GLD_LDS16(Ag0 + k0, lA0);
    GLD_LDS16(Ag1 + k0, lA1);
    GLD_LDS16(Bg0 + k0, lB0);
    GLD_LDS16(Bg1 + k0, lB1);
    __syncthreads();
    short8 af[4], bfv[4];
#pragma unroll
    for (int mi = 0; mi < 4; ++mi)
      af[mi] = *(const short8*)&lA[(wrow + mi * 16 + fr) * 32 + fq * 8];
#pragma unroll
    for (int ni = 0; ni < 4; ++ni)
      bfv[ni] = *(const short8*)&lB[(wcol + ni * 16 + fr) * 32 + fq * 8];
#pragma unroll
    for (int mi = 0; mi < 4; ++mi)
#pragma unroll
      for (int ni = 0; ni < 4; ++ni)
        acc[mi][ni] = mfma16(af[mi], bfv[ni], acc[mi][ni]);
  }

  const int lrow = fq * 4;
  if (epi == 0) {
#pragma unroll
    for (int mi = 0; mi < 4; ++mi)
#pragma unroll
      for (int ni = 0; ni < 4; ++ni)
#pragma unroll
        for (int r = 0; r < 4; ++r) {
          int t = m0 + wrow + mi * 16 + lrow + r;
          int e = n0 + wcol + ni * 16 + fr;
          int sect = e >> 10, eh = (e >> 6) & 15, dh = e & 63;
          int b = t >> 11, tt = t & 2047;
          size_t idx = (((size_t)b * 16 + eh) * 2048 + tt) * 64 + dh;
          bf16 val = __float2bfloat16(acc[mi][ni][r]);
          if (sect == 0) Qb[idx] = val;
          else if (sect == 1) Kb[idx] = val;
          else Vb[idx] = val;
        }
  } else {
#pragma unroll
    for (int mi = 0; mi < 4; ++mi)
#pragma unroll
      for (int ni = 0; ni < 4; ++ni)
#pragma unroll
        for (int r = 0; r < 4; ++r) {
          int t = m0 + wrow + mi * 16 + lrow + r;
          int e = n0 + wcol + ni * 16 + fr;
          Out[(size_t)t * N + e] = acc[mi][ni][r] + bias[e];
        }
  }
}

// ---------------- V transpose: [bh][2048][64] -> [bh][64][2048] -------------
__global__ __launch_bounds__(256) void k_trv(const bf16* __restrict__ Vb,
                                             bf16* __restrict__ Vt) {
  __shared__ bf16 tile[64][80];
  const int bh = blockIdx.y, t0 = blockIdx.x * 64;
  const int tid = threadIdx.x;
#pragma unroll
  for (int it = 0; it < 2; ++it) {
    int idx = tid + it * 256;
    int r = idx >> 3, c8 = (idx & 7) * 8;
    short8 v = *(const short8*)(Vb + ((size_t)bh * 2048 + t0 + r) * 64 + c8);
    *(short8*)&tile[r][c8] = v;
  }
  __syncthreads();
#pragma unroll
  for (int it = 0; it < 2; ++it) {
    int idx = tid + it * 256;
    int d = idx >> 3, c8 = (idx & 7) * 8;
    short8 o;
#pragma unroll
    for (int j = 0; j < 8; ++j)
      o[j] = __builtin_bit_cast(short, tile[c8 + j][d]);
    *(short8*)(Vt + ((size_t)bh * 64 + d) * 2048 + t0 + c8) = o;
  }
}

// ---------------- flash attention, 32x32 MFMA, in-register P ----------------
// 256 thr = 4 waves, wave owns 32 q-rows (block: 128 q). Swapped mfma(K,Q):
// lane holds col q = lane&31, 16 kv rows per 32-block. Softmax per-lane
// scalar m/l; pair (lane^32) combine via __shfl_xor (NOT permlane: copies
// coalesce). P-frags for PV built in-register (pk2 + permlane swap of
// DISTINCT values) -> zero LDS traffic for P.
__global__ __launch_bounds__(256, 2) void k_attn(
    const bf16* __restrict__ Qb, const bf16* __restrict__ Kb,
    const bf16* __restrict__ Vt, const float* __restrict__ relpf,
    bf16* __restrict__ AO) {
  __shared__ bf16 lK[2][4096];  // [64 kv][64 d], chunk-XOR-swizzled
  __shared__ bf16 lV[2][4096];  // [64 d][64 kv], chunk-XOR-swizzled

  const int id = blockIdx.x;            // 0..511
  const int xcd = id & 7, j = id >> 3;  // j: 0..63
  const int bh = xcd * 4 + (j >> 4), qt = j & 15;
  const int h = bh & 15, b = bh >> 4;
  const int tid = threadIdx.x, w = tid >> 6, l = tid & 63;
  const int r32 = l & 31, hl = l >> 5, rs7 = r32 & 7;
  const int q0w = qt * 128 + w * 32;

  const bf16* Kbh = Kb + (size_t)bh * 2048 * 64;
  const bf16* Vbh = Vt + (size_t)bh * 64 * 2048;
  // staging: 512 chunks of 16B; thread covers c = tid and tid+256
  const int r0 = tid >> 3, c0s = ((tid & 7) ^ (r0 & 7)) * 8;
  const int r1 = (tid + 256) >> 3, c1s = ((tid & 7) ^ (r1 & 7)) * 8;
  const bf16* Ks0 = Kbh + (size_t)r0 * 64 + c0s;
  const bf16* Ks1 = Kbh + (size_t)r1 * 64 + c1s;
  const bf16* Vs0 = Vbh + (size_t)r0 * 2048 + c0s;
  const bf16* Vs1 = Vbh + (size_t)r1 * 2048 + c1s;

  // Q as B-operand: col q = r32, k(d) = ks*16 + hl*8 + j
  const bf16* Qp = Qb + ((size_t)bh * 2048 + q0w + r32) * 64;
  short8 qf[4];
#pragma unroll
  for (int ks = 0; ks < 4; ++ks)
    qf[ks] = *(const short8*)(Qp + ks * 16 + hl * 8);

  // bias: idx = kv - q + 2047; kv = kt + kb*32 + (reg&3) + 8*(reg>>2) + 4*hl
  const float* bp = relpf + h * 4096 + (2047 + 4 * hl - q0w - r32);

  float m2 = -3e38f, ll = 0.f;
  f32x16 o[2] = {};

  GLD_LDS16(Ks0, &lK[0][tid * 8]);
  GLD_LDS16(Ks1, &lK[0][(tid + 256) * 8]);
  GLD_LDS16(Vs0, &lV[0][tid * 8]);
  GLD_LDS16(Vs1, &lV[0][(tid + 256) * 8]);
  __syncthreads();

  int cur = 0;
  for (int t = 0; t < 32; ++t) {
    const int kt = t * 64;
    if (t < 31) {  // next-tile stage overlaps this tile's compute
      GLD_LDS16(Ks0 + (size_t)(kt + 64) * 64, &lK[cur ^ 1][tid * 8]);
      GLD_LDS16(Ks1 + (size_t)(kt + 64) * 64, &lK[cur ^ 1][(tid + 256) * 8]);
      GLD_LDS16(Vs0 + (kt + 64), &lV[cur ^ 1][tid * 8]);
      GLD_LDS16(Vs1 + (kt + 64), &lV[cur ^ 1][(tid + 256) * 8]);
    }
    // ---- S^T = K Q^T : C[kv][q], lane: q = r32, kv rows per reg
    f32x16 s[2] = {};
    __builtin_amdgcn_s_setprio(1);
#pragma unroll
    for (int ks = 0; ks < 4; ++ks) {
      int cc = ((2 * ks + hl) ^ rs7) * 8;
      short8 k0 = *(const short8*)&lK[cur][r32 * 64 + cc];
      short8 k1 = *(const short8*)&lK[cur][(32 + r32) * 64 + cc];
      s[0] = mfma32(k0, qf[ks], s[0]);
      s[1] = mfma32(k1, qf[ks], s[1]);
    }
    __builtin_amdgcn_s_setprio(0);
    // ---- bias + scale (log2 domain), lane-local max
    float mxa = -3e38f, mxb = -3e38f;
#pragma unroll
    for (int reg = 0; reg < 16; ++reg) {
      int off = kt + (reg & 3) + 8 * (reg >> 2);
      float b0 = bp[off];
      float b1 = bp[off + 32];
      s[0][reg] = fmaf(s[0][reg], 0.18033688f, b0);
      s[1][reg] = fmaf(s[1][reg], 0.18033688f, b1);
      mxa = fmaxf(mxa, s[0][reg]);
      mxb = fmaxf(mxb, s[1][reg]);
    }
    float mo = fmaxf(mxa, mxb);
    float mx = fmaxf(mo, __shfl_xor(mo, 32));  // pair-combine (lane ^ 32)
    if (__any(mx > m2 + 8.f)) {  // defer-max: rescale only on real growth
      float nm = fmaxf(m2, mx);
      float fac = exp2f(m2 - nm);
      m2 = nm;
      ll *= fac;
#pragma unroll
      for (int reg = 0; reg < 16; ++reg) {
        o[0][reg] *= fac;
        o[1][reg] *= fac;
      }
    }
    float rsa = 0.f, rsb = 0.f;
#pragma unroll
    for (int reg = 0; reg < 16; ++reg) {
      s[0][reg] = exp2f(s[0][reg] - m2);
      rsa += s[0][reg];
      s[1][reg] = exp2f(s[1][reg] - m2);
      rsb += s[1][reg];
    }
    float rso = rsa + rsb;
    ll += rso + __shfl_xor(rso, 32);  // pair-combine (lane ^ 32)
    // ---- P-frags in-register + PV: O^T[d][q] += V^T P
#pragma unroll
    for (int kb = 0; kb < 2; ++kb) {
#pragma unroll
      for (int kh = 0; kh < 2; ++kh) {  // ks = kb*2 + kh
        const int e = kh * 8;
        unsigned a0 = pk2(s[kb][e + 0], s[kb][e + 1]);
        unsigned a1 = pk2(s[kb][e + 2], s[kb][e + 3]);
        unsigned b0 = pk2(s[kb][e + 4], s[kb][e + 5]);
        unsigned b1 = pk2(s[kb][e + 6], s[kb][e + 7]);
        PLSWAP(a0, b0);  // distinct values: no coalescing hazard
        PLSWAP(a1, b1);
        u32x4 pw = {a0, a1, b0, b1};
        short8 pf = __builtin_bit_cast(short8, pw);
        const int ks = kb * 2 + kh;
        const int cc = ((2 * ks + hl) ^ rs7) * 8;
        short8 v0 = *(const short8*)&lV[cur][r32 * 64 + cc];
        short8 v1 = *(const short8*)&lV[cur][(32 + r32) * 64 + cc];
        __builtin_amdgcn_s_setprio(1);
        o[0] = mfma32(v0, pf, o[0]);
        o[1] = mfma32(v1, pf, o[1]);
        __builtin_amdgcn_s_setprio(0);
      }
    }
    if (t < 31) __syncthreads();
    cur ^= 1;
  }

  // lane: q = r32; o[db][reg] = O^T[d = db*32 + (reg&3)+8*(reg>>2)+4*hl][q]
  float rin = 1.f / ll;
  bf16* aor = AO + ((size_t)(b * 2048 + q0w + r32)) * 1024 + h * 64 + hl * 4;
#pragma unroll
  for (int rg = 0; rg < 4; ++rg) {
    u32x2 ov0, ov1;
    ov0[0] = pk2(o[0][4 * rg + 0] * rin, o[0][4 * rg + 1] * rin);
    ov0[1] = pk2(o[0][4 * rg + 2] * rin, o[0][4 * rg + 3] * rin);
    *(u32x2*)(aor + rg * 8) = ov0;
    ov1[0] = pk2(o[1][4 * rg + 0] * rin, o[1][4 * rg + 1] * rin);
    ov1[1] = pk2(o[1][4 * rg + 2] * rin, o[1][4 * rg + 3] * rin);
    *(u32x2*)(aor + 32 + rg * 8) = ov1;
  }
}

// ---------------------------------------------------------------------------
extern "C" void kernel_launch(void* const* d_in, const int* in_sizes, int n_in,
                              void* d_out, int out_size, void* d_ws,
                              size_t ws_size, hipStream_t stream) {
  const float* x = (const float*)d_in[0];     // [2,2048,1024]
  const float* Wqkv = (const float*)d_in[1];  // [3072,1024]
  const float* Wout = (const float*)d_in[2];  // [1024,1024]
  const float* bout = (const float*)d_in[3];  // [1024]
  const float* rel = (const float*)d_in[4];   // [2049,16]
  float* out = (float*)d_out;

  char* p = (char*)d_ws;
  bf16* xb  = (bf16*)(p);                      // 8 MB  [4096][1024]
  bf16* wqb = (bf16*)(p + (8ull << 20));       // 6 MB  [3072][1024]
  bf16* wob = (bf16*)(p + (14ull << 20));      // 2 MB  [1024][1024]
  bf16* Qb  = (bf16*)(p + (16ull << 20));      // 8 MB  [32][2048][64]
  bf16* Kb  = (bf16*)(p + (24ull << 20));      // 8 MB
  bf16* Vb  = (bf16*)(p + (32ull << 20));      // 8 MB
  bf16* Vt  = (bf16*)(p + (40ull << 20));      // 8 MB  [32][64][2048]
  bf16* aob = (bf16*)(p + (48ull << 20));      // 8 MB  [4096][1024]
  float* relpf = (float*)(p + (56ull << 20));  // 256 KB [16][4096] f32

  k_cvt<<<4096, 256, 0, stream>>>(x, xb);
  k_cvt<<<3072, 256, 0, stream>>>(Wqkv, wqb);
  k_cvt<<<1024, 256, 0, stream>>>(Wout, wob);
  k_bias<<<256, 256, 0, stream>>>(rel, relpf);
  k_gemm<<<dim3(32, 24), 256, 0, stream>>>(xb, wqb, 4096, 3072, 1024, 0,
                                           Qb, Kb, Vb, nullptr, nullptr);
  k_trv<<<dim3(32, 32), 256, 0, stream>>>(Vb, Vt);
  k_attn<<<512, 256, 0, stream>>>(Qb, Kb, Vt, relpf, aob);
  k_gemm<<<dim3(32, 8), 256, 0, stream>>>(aob, wob, 4096, 1024, 1024, 1,
                                          nullptr, nullptr, nullptr, out, bout);
}

// Round 6
// 175.159 us; speedup vs baseline: 2.4295x; 1.0130x over previous
//
#include <hip/hip_runtime.h>
#include <hip/hip_bf16.h>

typedef __attribute__((ext_vector_type(8))) short short8;
typedef __attribute__((ext_vector_type(4))) float f32x4;
typedef __attribute__((ext_vector_type(16))) float f32x16;
typedef __attribute__((ext_vector_type(4))) unsigned short u16x4;
typedef __attribute__((ext_vector_type(2))) unsigned int u32x2;
typedef __attribute__((ext_vector_type(4))) unsigned int u32x4;
typedef __hip_bfloat16 bf16;

#define SCALE_Q 0.18033688f  // d^-0.5 * log2(e)

#define GLD_LDS16(g, l) __builtin_amdgcn_global_load_lds(                      \
    (const __attribute__((address_space(1))) void*)(g),                        \
    (__attribute__((address_space(3))) void*)(l), 16, 0, 0)

static __device__ __forceinline__ f32x4 mfma16(short8 a, short8 b, f32x4 c) {
  return __builtin_amdgcn_mfma_f32_16x16x32_bf16(a, b, c, 0, 0, 0);
}
static __device__ __forceinline__ f32x16 mfma32(short8 a, short8 b, f32x16 c) {
  return __builtin_amdgcn_mfma_f32_32x32x16_bf16(a, b, c, 0, 0, 0);
}

// packed f32x2 -> bf16x2 convert (single HW instr; no builtin on gfx950)
static __device__ __forceinline__ unsigned cvtpk(float lo, float hi) {
  unsigned r;
  asm("v_cvt_pk_bf16_f32 %0, %1, %2" : "=v"(r) : "v"(lo), "v"(hi));
  return r;
}

// vdst upper 32 lanes <-> vsrc lower 32 lanes. ONLY use with operands that
// hold DISTINCT values (identical-copy operands can be register-coalesced by
// the allocator -> self-swap bug; scalar reductions use __shfl_xor instead).
#define PLSWAP(a, b) asm("v_permlane32_swap_b32 %0, %1" : "+v"(a), "+v"(b))

// ---------------- fp32 -> bf16 convert (vectorized, exact-grid) -------------
__global__ __launch_bounds__(256) void k_cvt(const float* __restrict__ in,
                                             bf16* __restrict__ out) {
  long i = (long)blockIdx.x * 256 + threadIdx.x;
  f32x4 v = *(const f32x4*)(in + i * 4);
  u16x4 o;
#pragma unroll
  for (int j = 0; j < 4; ++j)
    o[j] = __builtin_bit_cast(unsigned short, __float2bfloat16(v[j]));
  *(u16x4*)((unsigned short*)out + i * 4) = o;
}

// ---------------- per-head bias table, clamp baked, log2e prescaled, f32 ----
// relpf[h][i] = rel[clamp(i-2047,±1024)+1024][h] * log2(e),  i in [0,4096)
__global__ __launch_bounds__(256) void k_bias(const float* __restrict__ rel,
                                              float* __restrict__ relpf) {
  int i = blockIdx.x * 256 + threadIdx.x;  // 0..65535
  int h = i >> 12, ii = i & 4095;
  int dd = ii - 2047;
  dd = dd < -1024 ? -1024 : (dd > 1024 ? 1024 : dd);
  relpf[i] = rel[(size_t)(dd + 1024) * 16 + h] * 1.44269504f;
}

// ---------------- 128x128 bf16 GEMM, B stored [N][K] (K-major) --------------
// mfma operands SWAPPED (bfv, af) -> lane holds 4 consecutive N-columns:
// D[row = e = fq*4+reg (N-dim), col = t = fr (M-dim)] -> packed stores.
// epi==0: scatter into Q/K/V [bh][2048][64], Q pre-scaled by SCALE_Q.
// epi==1: fp32 out[t*N+e] = acc + bias[e], 16B stores.
__global__ __launch_bounds__(256) void k_gemm(
    const bf16* __restrict__ A, const bf16* __restrict__ B,
    int M, int N, int K, int epi,
    bf16* __restrict__ Qb, bf16* __restrict__ Kb, bf16* __restrict__ Vb,
    float* __restrict__ Out, const float* __restrict__ bias) {
  __shared__ bf16 lA[4096];  // 128 x 32
  __shared__ bf16 lB[4096];  // 128 x 32
  const int tid = threadIdx.x, w = tid >> 6, l = tid & 63;
  const int m0 = blockIdx.x * 128, n0 = blockIdx.y * 128;
  const int wrow = (w >> 1) * 64, wcol = (w & 1) * 64;
  const int fr = l & 15, fq = l >> 4;
  f32x4 acc[4][4] = {};
  const int c0 = w * 64 + l, c1 = c0 + 256;  // 16B chunk ids
  const bf16* Ag0 = A + (size_t)(m0 + (c0 >> 2)) * K + (c0 & 3) * 8;
  const bf16* Ag1 = A + (size_t)(m0 + (c1 >> 2)) * K + (c1 & 3) * 8;
  const bf16* Bg0 = B + (size_t)(n0 + (c0 >> 2)) * K + (c0 & 3) * 8;
  const bf16* Bg1 = B + (size_t)(n0 + (c1 >> 2)) * K + (c1 & 3) * 8;
  bf16* lA0 = &lA[w * 512];
  bf16* lA1 = &lA[2048 + w * 512];
  bf16* lB0 = &lB[w * 512];
  bf16* lB1 = &lB[2048 + w * 512];

  for (int k0 = 0; k0 < K; k0 += 32) {
    __syncthreads();
    GLD_LDS16(Ag0 + k0, lA0);
    GLD_LDS16(Ag1 + k0, lA1);
    GLD_LDS16(Bg0 + k0, lB0);
    GLD_LDS16(Bg1 + k0, lB1);
    __syncthreads();
    short8 af[4], bfv[4];
#pragma unroll
    for (int mi = 0; mi < 4; ++mi)
      af[mi] = *(const short8*)&lA[(wrow + mi * 16 + fr) * 32 + fq * 8];
#pragma unroll
    for (int ni = 0; ni < 4; ++ni)
      bfv[ni] = *(const short8*)&lB[(wcol + ni * 16 + fr) * 32 + fq * 8];
#pragma unroll
    for (int mi = 0; mi < 4; ++mi)
#pragma unroll
      for (int ni = 0; ni < 4; ++ni)
        acc[mi][ni] = mfma16(bfv[ni], af[mi], acc[mi][ni]);  // transposed
  }

  if (epi == 0) {
#pragma unroll
    for (int mi = 0; mi < 4; ++mi)
#pragma unroll
      for (int ni = 0; ni < 4; ++ni) {
        int t = m0 + wrow + mi * 16 + fr;          // lane-fixed token
        int e4 = n0 + wcol + ni * 16 + fq * 4;     // 4 consecutive cols
        int sect = e4 >> 10, eh = (e4 >> 6) & 15, dh = e4 & 63;
        int b = t >> 11, tt = t & 2047;
        size_t idx = (((size_t)b * 16 + eh) * 2048 + tt) * 64 + dh;
        f32x4 a = acc[mi][ni];
        float sc = (sect == 0) ? SCALE_Q : 1.f;  // pre-scale Q for attention
        u32x2 ov;
        ov[0] = cvtpk(a[0] * sc, a[1] * sc);
        ov[1] = cvtpk(a[2] * sc, a[3] * sc);
        bf16* dst = (sect == 0) ? Qb : (sect == 1) ? Kb : Vb;
        *(u32x2*)(dst + idx) = ov;
      }
  } else {
#pragma unroll
    for (int mi = 0; mi < 4; ++mi)
#pragma unroll
      for (int ni = 0; ni < 4; ++ni) {
        int t = m0 + wrow + mi * 16 + fr;
        int e4 = n0 + wcol + ni * 16 + fq * 4;
        f32x4 bv = *(const f32x4*)(bias + e4);
        f32x4 a = acc[mi][ni];
        f32x4 o = {a[0] + bv[0], a[1] + bv[1], a[2] + bv[2], a[3] + bv[3]};
        *(f32x4*)(Out + (size_t)t * N + e4) = o;
      }
  }
}

// ---------------- V transpose: [bh][2048][64] -> [bh][64][2048] -------------
__global__ __launch_bounds__(256) void k_trv(const bf16* __restrict__ Vb,
                                             bf16* __restrict__ Vt) {
  __shared__ bf16 tile[64][80];
  const int bh = blockIdx.y, t0 = blockIdx.x * 64;
  const int tid = threadIdx.x;
#pragma unroll
  for (int it = 0; it < 2; ++it) {
    int idx = tid + it * 256;
    int r = idx >> 3, c8 = (idx & 7) * 8;
    short8 v = *(const short8*)(Vb + ((size_t)bh * 2048 + t0 + r) * 64 + c8);
    *(short8*)&tile[r][c8] = v;
  }
  __syncthreads();
#pragma unroll
  for (int it = 0; it < 2; ++it) {
    int idx = tid + it * 256;
    int d = idx >> 3, c8 = (idx & 7) * 8;
    short8 o;
#pragma unroll
    for (int j = 0; j < 8; ++j)
      o[j] = __builtin_bit_cast(short, tile[c8 + j][d]);
    *(short8*)(Vt + ((size_t)bh * 64 + d) * 2048 + t0 + c8) = o;
  }
}

// ---------------- flash attention, 32x32 MFMA, in-register P ----------------
// 256 thr = 4 waves, wave owns 32 q-rows. Swapped mfma(K,Q): lane holds col
// q = lane&31. QK accumulator SEEDED with rel-bias (Q pre-scaled in gemm) ->
// no bias-fma pass; bias for tile t+1 prefetched during tile t. Softmax
// per-lane scalar; pair (lane^32) combine via __shfl_xor. P-frags built
// in-register (cvt_pk + permlane swap) -> zero LDS traffic for P.
__global__ __launch_bounds__(256, 2) void k_attn(
    const bf16* __restrict__ Qb, const bf16* __restrict__ Kb,
    const bf16* __restrict__ Vt, const float* __restrict__ relpf,
    bf16* __restrict__ AO) {
  __shared__ bf16 lK[2][4096];  // [64 kv][64 d], chunk-XOR-swizzled
  __shared__ bf16 lV[2][4096];  // [64 d][64 kv], chunk-XOR-swizzled

  const int id = blockIdx.x;            // 0..511
  const int xcd = id & 7, j = id >> 3;  // j: 0..63
  const int bh = xcd * 4 + (j >> 4), qt = j & 15;
  const int h = bh & 15, b = bh >> 4;
  const int tid = threadIdx.x, w = tid >> 6, l = tid & 63;
  const int r32 = l & 31, hl = l >> 5, rs7 = r32 & 7;
  const int q0w = qt * 128 + w * 32;

  const bf16* Kbh = Kb + (size_t)bh * 2048 * 64;
  const bf16* Vbh = Vt + (size_t)bh * 64 * 2048;
  // staging: 512 chunks of 16B; thread covers c = tid and tid+256
  const int r0 = tid >> 3, c0s = ((tid & 7) ^ (r0 & 7)) * 8;
  const int r1 = (tid + 256) >> 3, c1s = ((tid & 7) ^ (r1 & 7)) * 8;
  const bf16* Ks0 = Kbh + (size_t)r0 * 64 + c0s;
  const bf16* Ks1 = Kbh + (size_t)r1 * 64 + c1s;
  const bf16* Vs0 = Vbh + (size_t)r0 * 2048 + c0s;
  const bf16* Vs1 = Vbh + (size_t)r1 * 2048 + c1s;

  // Q as B-operand: col q = r32, k(d) = ks*16 + hl*8 + j  (pre-scaled)
  const bf16* Qp = Qb + ((size_t)bh * 2048 + q0w + r32) * 64;
  short8 qf[4];
#pragma unroll
  for (int ks = 0; ks < 4; ++ks)
    qf[ks] = *(const short8*)(Qp + ks * 16 + hl * 8);

  // bias: idx = kv - q + 2047; kv = kt + kb*32 + (reg&3) + 8*(reg>>2) + 4*hl
  const float* bp = relpf + h * 4096 + (2047 + 4 * hl - q0w - r32);

#define LOADB(d0, d1, KT)                                                      \
  do {                                                                         \
    _Pragma("unroll") for (int reg = 0; reg < 16; ++reg) {                     \
      int off = (KT) + (reg & 3) + 8 * (reg >> 2);                             \
      d0[reg] = bp[off];                                                       \
      d1[reg] = bp[off + 32];                                                  \
    }                                                                          \
  } while (0)

  float m2 = -3e38f, ll = 0.f;
  f32x16 o[2] = {};
  f32x16 bc0, bc1;  // bias for current tile (prefetched)
  LOADB(bc0, bc1, 0);

  GLD_LDS16(Ks0, &lK[0][tid * 8]);
  GLD_LDS16(Ks1, &lK[0][(tid + 256) * 8]);
  GLD_LDS16(Vs0, &lV[0][tid * 8]);
  GLD_LDS16(Vs1, &lV[0][(tid + 256) * 8]);
  __syncthreads();

  int cur = 0;
  for (int t = 0; t < 32; ++t) {
    const int kt = t * 64;
    if (t < 31) {  // next-tile stage overlaps this tile's compute
      GLD_LDS16(Ks0 + (size_t)(kt + 64) * 64, &lK[cur ^ 1][tid * 8]);
      GLD_LDS16(Ks1 + (size_t)(kt + 64) * 64, &lK[cur ^ 1][(tid + 256) * 8]);
      GLD_LDS16(Vs0 + (kt + 64), &lV[cur ^ 1][tid * 8]);
      GLD_LDS16(Vs1 + (kt + 64), &lV[cur ^ 1][(tid + 256) * 8]);
    }
    // ---- S^T = K Q^T + bias : C-in seeded with bias (Q pre-scaled)
    f32x16 s0 = bc0, s1 = bc1;
    __builtin_amdgcn_s_setprio(1);
#pragma unroll
    for (int ks = 0; ks < 4; ++ks) {
      int cc = ((2 * ks + hl) ^ rs7) * 8;
      short8 k0 = *(const short8*)&lK[cur][r32 * 64 + cc];
      short8 k1 = *(const short8*)&lK[cur][(32 + r32) * 64 + cc];
      s0 = mfma32(k0, qf[ks], s0);
      s1 = mfma32(k1, qf[ks], s1);
    }
    __builtin_amdgcn_s_setprio(0);
    if (t < 31) LOADB(bc0, bc1, kt + 64);  // prefetch next tile's bias
    // ---- lane-local max, 4 chains (depth 8)
    float ma[4] = {-3e38f, -3e38f, -3e38f, -3e38f};
#pragma unroll
    for (int reg = 0; reg < 16; ++reg) {
      ma[reg & 3] = fmaxf(ma[reg & 3], fmaxf(s0[reg], s1[reg]));
    }
    float mo = fmaxf(fmaxf(ma[0], ma[1]), fmaxf(ma[2], ma[3]));
    float mx = fmaxf(mo, __shfl_xor(mo, 32));  // pair-combine (lane ^ 32)
    if (__any(mx > m2 + 8.f)) {  // defer-max: rescale only on real growth
      float nm = fmaxf(m2, mx);
      float fac = exp2f(m2 - nm);
      m2 = nm;
      ll *= fac;
#pragma unroll
      for (int reg = 0; reg < 16; ++reg) {
        o[0][reg] *= fac;
        o[1][reg] *= fac;
      }
    }
    // ---- exp2 + sum, 4 chains
    float ra[4] = {0.f, 0.f, 0.f, 0.f};
#pragma unroll
    for (int reg = 0; reg < 16; ++reg) {
      s0[reg] = exp2f(s0[reg] - m2);
      s1[reg] = exp2f(s1[reg] - m2);
      ra[reg & 3] += s0[reg] + s1[reg];
    }
    float rso = (ra[0] + ra[1]) + (ra[2] + ra[3]);
    ll += rso + __shfl_xor(rso, 32);  // pair-combine (lane ^ 32)
    // ---- P-frags in-register + PV: O^T[d][q] += V^T P
#pragma unroll
    for (int kb = 0; kb < 2; ++kb) {
      const f32x16& sv = kb ? s1 : s0;
#pragma unroll
      for (int kh = 0; kh < 2; ++kh) {  // ks = kb*2 + kh
        const int e = kh * 8;
        unsigned a0 = cvtpk(sv[e + 0], sv[e + 1]);
        unsigned a1 = cvtpk(sv[e + 2], sv[e + 3]);
        unsigned b0 = cvtpk(sv[e + 4], sv[e + 5]);
        unsigned b1 = cvtpk(sv[e + 6], sv[e + 7]);
        PLSWAP(a0, b0);  // distinct values: no coalescing hazard
        PLSWAP(a1, b1);
        u32x4 pw = {a0, a1, b0, b1};
        short8 pf = __builtin_bit_cast(short8, pw);
        const int ks = kb * 2 + kh;
        const int cc = ((2 * ks + hl) ^ rs7) * 8;
        short8 v0 = *(const short8*)&lV[cur][r32 * 64 + cc];
        short8 v1 = *(const short8*)&lV[cur][(32 + r32) * 64 + cc];
        __builtin_amdgcn_s_setprio(1);
        o[0] = mfma32(v0, pf, o[0]);
        o[1] = mfma32(v1, pf, o[1]);
        __builtin_amdgcn_s_setprio(0);
      }
    }
    if (t < 31) __syncthreads();
    cur ^= 1;
  }

  // lane: q = r32; o[db][reg] = O^T[d = db*32 + (reg&3)+8*(reg>>2)+4*hl][q]
  float rin = 1.f / ll;
  bf16* aor = AO + ((size_t)(b * 2048 + q0w + r32)) * 1024 + h * 64 + hl * 4;
#pragma unroll
  for (int rg = 0; rg < 4; ++rg) {
    u32x2 ov0, ov1;
    ov0[0] = cvtpk(o[0][4 * rg + 0] * rin, o[0][4 * rg + 1] * rin);
    ov0[1] = cvtpk(o[0][4 * rg + 2] * rin, o[0][4 * rg + 3] * rin);
    *(u32x2*)(aor + rg * 8) = ov0;
    ov1[0] = cvtpk(o[1][4 * rg + 0] * rin, o[1][4 * rg + 1] * rin);
    ov1[1] = cvtpk(o[1][4 * rg + 2] * rin, o[1][4 * rg + 3] * rin);
    *(u32x2*)(aor + 32 + rg * 8) = ov1;
  }
#undef LOADB
}

// ---------------------------------------------------------------------------
extern "C" void kernel_launch(void* const* d_in, const int* in_sizes, int n_in,
                              void* d_out, int out_size, void* d_ws,
                              size_t ws_size, hipStream_t stream) {
  const float* x = (const float*)d_in[0];     // [2,2048,1024]
  const float* Wqkv = (const float*)d_in[1];  // [3072,1024]
  const float* Wout = (const float*)d_in[2];  // [1024,1024]
  const float* bout = (const float*)d_in[3];  // [1024]
  const float* rel = (const float*)d_in[4];   // [2049,16]
  float* out = (float*)d_out;

  char* p = (char*)d_ws;
  bf16* xb  = (bf16*)(p);                      // 8 MB  [4096][1024]
  bf16* wqb = (bf16*)(p + (8ull << 20));       // 6 MB  [3072][1024]
  bf16* wob = (bf16*)(p + (14ull << 20));      // 2 MB  [1024][1024]
  bf16* Qb  = (bf16*)(p + (16ull << 20));      // 8 MB  [32][2048][64]
  bf16* Kb  = (bf16*)(p + (24ull << 20));      // 8 MB
  bf16* Vb  = (bf16*)(p + (32ull << 20));      // 8 MB
  bf16* Vt  = (bf16*)(p + (40ull << 20));      // 8 MB  [32][64][2048]
  bf16* aob = (bf16*)(p + (48ull << 20));      // 8 MB  [4096][1024]
  float* relpf = (float*)(p + (56ull << 20));  // 256 KB [16][4096] f32

  k_cvt<<<4096, 256, 0, stream>>>(x, xb);
  k_cvt<<<3072, 256, 0, stream>>>(Wqkv, wqb);
  k_cvt<<<1024, 256, 0, stream>>>(Wout, wob);
  k_bias<<<256, 256, 0, stream>>>(rel, relpf);
  k_gemm<<<dim3(32, 24), 256, 0, stream>>>(xb, wqb, 4096, 3072, 1024, 0,
                                           Qb, Kb, Vb, nullptr, nullptr);
  k_trv<<<dim3(32, 32), 256, 0, stream>>>(Vb, Vt);
  k_attn<<<512, 256, 0, stream>>>(Qb, Kb, Vt, relpf, aob);
  k_gemm<<<dim3(32, 8), 256, 0, stream>>>(aob, wob, 4096, 1024, 1024, 1,
                                          nullptr, nullptr, nullptr, out, bout);
}